// Round 1
// baseline (143.939 us; speedup 1.0000x reference)
//
#include <hip/hip_runtime.h>
#include <math.h>

// Distral per-task MLP: 32769 heads, h = relu(W1[3->100] x + b1),
// p = softmax(W2[100->5] h + b2).  ~3.6 KB read/head, ~119 MB total.
//
// R9: force memory-level parallelism.  rocprof showed VGPR_Count=24 --
// too few to hold the 9 float4 load results (36 VGPRs) -- proving the
// compiler serialized the "independent" loads into load->wait->use
// chains.  Wave-lifetime arithmetic (64 waves/CU over 97k cycles, ~21
// resident -> ~32k cycles/wave for 7 KB of reads) matches ~17 serial
// HBM round-trips.  That, not bandwidth, is the 3.4 TB/s cap all six
// prior structures shared.  Fix: sched_barrier(0) fence between the
// load phase and the compute phase so all 17 VMEM ops issue before any
// waitcnt, keeping ~7 KB/wave in flight.
// Structure otherwise = R8 (XCD-partitioned head order, register
// float4, lane owns hidden chunk 4c, two heads per wave in 32-lane
// halves).

#define N_HEADS 32769
#define HID     100
#define OUT     5
#define CHUNKS  25               // float4 chunks per head
#define PART    4100             // heads per XCD partition (8*4100 >= N_HEADS)
#define BLK_PER_PART 513         // ceil(4100/8 heads-per-block)

__global__ __launch_bounds__(256) void distral_kernel(
    const float* __restrict__ x,
    const float* __restrict__ W1,
    const float* __restrict__ b1,
    const float* __restrict__ W2,
    const float* __restrict__ b2,
    float* __restrict__ out)
{
    const int lane = threadIdx.x & 63;
    const int half = lane >> 5;          // 0/1: which head this half-wave owns
    const int ll   = lane & 31;
    const int wv   = threadIdx.x >> 6;

    // XCD swizzle: partition p = bid & 7 lands round-robin on XCD p,
    // and reads only heads [p*PART, p*PART+4100) -- contiguous ~15 MB.
    const int p    = blockIdx.x & 7;
    const int i    = blockIdx.x >> 3;            // 0..BLK_PER_PART-1
    const int slot = i * 8 + wv * 2 + half;      // head index within partition
    const int hraw = p * PART + slot;
    const bool valid = (slot < PART) && (hraw < N_HEADS);
    const int  head  = valid ? hraw : (N_HEADS - 1);   // clamp keeps loads legal

    const int c = (ll < CHUNKS) ? ll : (CHUNKS - 1);
    const bool active = (ll < CHUNKS);

    const float4* W1q = (const float4*)(W1 + (size_t)head * 300);  // 16B-aligned
    const float4* b1q = (const float4*)(b1 + (size_t)head * 100);
    const float4* W2q = (const float4*)(W2 + (size_t)head * 500);

    // ---- LOAD PHASE: 9 dwordx4 + 8 dword per lane, all independent ----
    const float4 q0 = W1q[3 * c + 0];    // W1 rows 4c..4c+3
    const float4 q1 = W1q[3 * c + 1];
    const float4 q2 = W1q[3 * c + 2];
    const float4 bq = b1q[c];
    float4 w2[OUT];
#pragma unroll
    for (int o = 0; o < OUT; ++o)
        w2[o] = W2q[CHUNKS * o + c];     // W2[o][4c..4c+3]

    const float x0 = x[head * 3 + 0];
    const float x1 = x[head * 3 + 1];
    const float x2 = x[head * 3 + 2];
    float b2v[OUT];
#pragma unroll
    for (int o = 0; o < OUT; ++o) b2v[o] = b2[head * OUT + o];

    // R9 fence: nothing below may be hoisted above, no load may sink
    // below.  Forces all 17 VMEM results simultaneously live (>=48
    // VGPR) so they are all in flight before the first s_waitcnt.
    __builtin_amdgcn_sched_barrier(0);

    // ---- layer 1: this lane's 4 hidden units, in-lane ----
    const float h0 = fmaxf(fmaf(q0.x, x0, fmaf(q0.y, x1, fmaf(q0.z, x2, bq.x))), 0.f);
    const float h1 = fmaxf(fmaf(q0.w, x0, fmaf(q1.x, x1, fmaf(q1.y, x2, bq.y))), 0.f);
    const float h2 = fmaxf(fmaf(q1.z, x0, fmaf(q1.w, x1, fmaf(q2.x, x2, bq.z))), 0.f);
    const float h3 = fmaxf(fmaf(q2.y, x0, fmaf(q2.z, x1, fmaf(q2.w, x2, bq.w))), 0.f);

    // ---- layer 2: per-lane dot4 + 32-half butterfly ----
    float logit[OUT];
#pragma unroll
    for (int o = 0; o < OUT; ++o) {
        float pt = fmaf(h0, w2[o].x, fmaf(h1, w2[o].y,
                   fmaf(h2, w2[o].z, h3 * w2[o].w)));
        pt = active ? pt : 0.0f;
#pragma unroll
        for (int m = 16; m > 0; m >>= 1)
            pt += __shfl_xor(pt, m, 64); // masks <32: stays within the half
        logit[o] = pt + b2v[o];
    }

    // ---- softmax (uniform within each half) ----
    float mx = -INFINITY;
#pragma unroll
    for (int o = 0; o < OUT; ++o) mx = fmaxf(mx, logit[o]);
    float e[OUT], s = 0.0f;
#pragma unroll
    for (int o = 0; o < OUT; ++o) { e[o] = __expf(logit[o] - mx); s += e[o]; }
    const float inv = 1.0f / s;

    if (valid && ll < OUT) {
        float v = (ll == 0) ? e[0]
                : (ll == 1) ? e[1]
                : (ll == 2) ? e[2]
                : (ll == 3) ? e[3]
                :             e[4];
        out[(size_t)head * OUT + ll] = v * inv;
    }
}

extern "C" void kernel_launch(void* const* d_in, const int* in_sizes, int n_in,
                              void* d_out, int out_size, void* d_ws, size_t ws_size,
                              hipStream_t stream) {
    const float* x  = (const float*)d_in[0];
    const float* W1 = (const float*)d_in[1];
    const float* b1 = (const float*)d_in[2];
    const float* W2 = (const float*)d_in[3];
    const float* b2 = (const float*)d_in[4];
    float* out = (float*)d_out;

    distral_kernel<<<8 * BLK_PER_PART, 256, 0, stream>>>(x, W1, b1, W2, b2, out);
}

// Round 2
// 143.000 us; speedup vs baseline: 1.0066x; 1.0066x over previous
//
#include <hip/hip_runtime.h>
#include <math.h>

// Distral per-task MLP: 32769 heads, h = relu(W1[3->100] x + b1),
// p = softmax(W2[100->5] h + b2).  ~3.6 KB read/head, ~119 MB total.
//
// R10: force memory-level parallelism via DATA dependence.
// R9's sched_barrier(0) was a no-op (VGPR stayed 24, time identical):
// the intrinsic doesn't write memory, so IR-level sinking moved loads
// past it before the machine scheduler ever saw it.  VGPR_Count=24 is
// proof the 9 float4 results were never simultaneously live -> loads
// ran as ~17 serial HBM round-trips (~1.9k cy each under load = the
// observed 32k-cycle wave lifetime).  Fix: empty asm volatile with
// "+v" constraints on EVERY load result.  An instruction that reads
// the values cannot be crossed by the loads at any compiler level, so
// codegen must be: 17 VMEM issues back-to-back -> one s_waitcnt ->
// compute.  ~9 KB/wave in flight vs ~1 KB before.
// Verification gate: VGPR_Count must jump to ~48-64.  If it does and
// time doesn't move, latency theory is falsified.
// Structure otherwise = R8 (XCD-partitioned head order, register
// float4, lane owns hidden chunk 4c, two heads per wave in 32-lane
// halves).

#define N_HEADS 32769
#define HID     100
#define OUT     5
#define CHUNKS  25               // float4 chunks per head
#define PART    4100             // heads per XCD partition (8*4100 >= N_HEADS)
#define BLK_PER_PART 513         // ceil(4100/8 heads-per-block)

typedef float f32x4 __attribute__((ext_vector_type(4)));

__global__ __launch_bounds__(256) void distral_kernel(
    const float* __restrict__ x,
    const float* __restrict__ W1,
    const float* __restrict__ b1,
    const float* __restrict__ W2,
    const float* __restrict__ b2,
    float* __restrict__ out)
{
    const int lane = threadIdx.x & 63;
    const int half = lane >> 5;          // 0/1: which head this half-wave owns
    const int ll   = lane & 31;
    const int wv   = threadIdx.x >> 6;

    // XCD swizzle: partition p = bid & 7 lands round-robin on XCD p,
    // and reads only heads [p*PART, p*PART+4100) -- contiguous ~15 MB.
    const int p    = blockIdx.x & 7;
    const int i    = blockIdx.x >> 3;            // 0..BLK_PER_PART-1
    const int slot = i * 8 + wv * 2 + half;      // head index within partition
    const int hraw = p * PART + slot;
    const bool valid = (slot < PART) && (hraw < N_HEADS);
    const int  head  = valid ? hraw : (N_HEADS - 1);   // clamp keeps loads legal

    const int c = (ll < CHUNKS) ? ll : (CHUNKS - 1);
    const bool active = (ll < CHUNKS);

    const f32x4* W1q = (const f32x4*)(W1 + (size_t)head * 300);  // 16B-aligned
    const f32x4* b1q = (const f32x4*)(b1 + (size_t)head * 100);
    const f32x4* W2q = (const f32x4*)(W2 + (size_t)head * 500);

    // ---- LOAD PHASE: all independent, no consumer until the asm fence ----
    f32x4 q0  = W1q[3 * c + 0];          // W1 rows 4c..4c+3 (12 floats)
    f32x4 q1  = W1q[3 * c + 1];
    f32x4 q2  = W1q[3 * c + 2];
    f32x4 bq  = b1q[c];
    f32x4 w20 = W2q[CHUNKS * 0 + c];     // W2[o][4c..4c+3]
    f32x4 w21 = W2q[CHUNKS * 1 + c];
    f32x4 w22 = W2q[CHUNKS * 2 + c];
    f32x4 w23 = W2q[CHUNKS * 3 + c];
    f32x4 w24 = W2q[CHUNKS * 4 + c];

    float x0 = x[head * 3 + 0];
    float x1 = x[head * 3 + 1];
    float x2 = x[head * 3 + 2];

    // b2 row: 5 floats, dword-aligned.  16B load (HW allows 4B-aligned
    // dwordx4) + 1 dword instead of 5 scalar loads.
    f32x4 b2a;
    __builtin_memcpy(&b2a, b2 + (size_t)head * OUT, sizeof(f32x4));
    float b2e = b2[(size_t)head * OUT + 4];

    // R10 fence: reads every load result -> all loads must issue before
    // this point, all compute after.  One batched waitcnt, ~9KB/wave in
    // flight.
    asm volatile("" :
        "+v"(q0), "+v"(q1), "+v"(q2), "+v"(bq),
        "+v"(w20), "+v"(w21), "+v"(w22), "+v"(w23), "+v"(w24),
        "+v"(x0), "+v"(x1), "+v"(x2), "+v"(b2a), "+v"(b2e));

    // ---- layer 1: this lane's 4 hidden units, in-lane ----
    const float h0 = fmaxf(fmaf(q0[0], x0, fmaf(q0[1], x1, fmaf(q0[2], x2, bq[0]))), 0.f);
    const float h1 = fmaxf(fmaf(q0[3], x0, fmaf(q1[0], x1, fmaf(q1[1], x2, bq[1]))), 0.f);
    const float h2 = fmaxf(fmaf(q1[2], x0, fmaf(q1[3], x1, fmaf(q2[0], x2, bq[2]))), 0.f);
    const float h3 = fmaxf(fmaf(q2[1], x0, fmaf(q2[2], x1, fmaf(q2[3], x2, bq[3]))), 0.f);

    // ---- layer 2: per-lane dot4 + 32-half butterfly ----
    const f32x4 w2arr[OUT] = { w20, w21, w22, w23, w24 };
    const float b2v[OUT]   = { b2a[0], b2a[1], b2a[2], b2a[3], b2e };

    float logit[OUT];
#pragma unroll
    for (int o = 0; o < OUT; ++o) {
        float pt = fmaf(h0, w2arr[o][0], fmaf(h1, w2arr[o][1],
                   fmaf(h2, w2arr[o][2], h3 * w2arr[o][3])));
        pt = active ? pt : 0.0f;
#pragma unroll
        for (int m = 16; m > 0; m >>= 1)
            pt += __shfl_xor(pt, m, 64); // masks <32: stays within the half
        logit[o] = pt + b2v[o];
    }

    // ---- softmax (uniform within each half) ----
    float mx = -INFINITY;
#pragma unroll
    for (int o = 0; o < OUT; ++o) mx = fmaxf(mx, logit[o]);
    float e[OUT], s = 0.0f;
#pragma unroll
    for (int o = 0; o < OUT; ++o) { e[o] = __expf(logit[o] - mx); s += e[o]; }
    const float inv = 1.0f / s;

    if (valid && ll < OUT) {
        float v = (ll == 0) ? e[0]
                : (ll == 1) ? e[1]
                : (ll == 2) ? e[2]
                : (ll == 3) ? e[3]
                :             e[4];
        out[(size_t)head * OUT + ll] = v * inv;
    }
}

extern "C" void kernel_launch(void* const* d_in, const int* in_sizes, int n_in,
                              void* d_out, int out_size, void* d_ws, size_t ws_size,
                              hipStream_t stream) {
    const float* x  = (const float*)d_in[0];
    const float* W1 = (const float*)d_in[1];
    const float* b1 = (const float*)d_in[2];
    const float* W2 = (const float*)d_in[3];
    const float* b2 = (const float*)d_in[4];
    float* out = (float*)d_out;

    distral_kernel<<<8 * BLK_PER_PART, 256, 0, stream>>>(x, W1, b1, W2, b2, out);
}